// Round 10
// baseline (4059.079 us; speedup 1.0000x reference)
//
#include <hip/hip_runtime.h>
#include <cstddef>
#include <cstdint>

#define TPB 256

typedef unsigned int u32;
typedef unsigned short u16;
typedef __bf16 bf16x8 __attribute__((ext_vector_type(8)));
typedef float f32x4 __attribute__((ext_vector_type(4)));

template<int ACT>
__device__ __forceinline__ float act_f(float v) {
  if (ACT == 1) return v >= 0.f ? v : 0.1f * v;          // lrelu
  if (ACT == 2) return 1.f / (1.f + expf(-v));           // sigmoid
  return v;
}

__device__ __forceinline__ u16 f2bf(float f) {
  __bf16 h = (__bf16)f;
  return __builtin_bit_cast(u16, h);
}
__device__ __forceinline__ u32 pk2bf(float a, float b) {
  return (u32)f2bf(a) | ((u32)f2bf(b) << 16);
}

// ---------------------------------------------------------------------------
// Weight prep (one launch, 22 convs): fp32 [Cout][Cin][3][3] -> bf16
// [kc][tap][co(pad)][40].
// ---------------------------------------------------------------------------
struct WPrepArgs {
  const float* src[22];
  u16* dst[22];
  int cin[22], cout[22], coutpad[22], total[22];
};

__global__ void k_wprep_all(WPrepArgs a)
{
  const int seg = blockIdx.y;
  const int idx = blockIdx.x * TPB + threadIdx.x;
  if (idx >= a.total[seg]) return;
  const int Cin = a.cin[seg], Cout = a.cout[seg], Coutpad = a.coutpad[seg];
  int kk = idx % 40; int t = idx / 40;
  int co = t % Coutpad; t /= Coutpad;
  int tap = t % 9; int kc = t / 9;
  u16 v = 0;
  if (kk < 32 && co < Cout)
    v = f2bf(a.src[seg][((size_t)co * Cin + kc * 32 + kk) * 9 + tap]);
  a.dst[seg][idx] = v;
}

// ---------------------------------------------------------------------------
// Input prep: fp32 planar [2][64][HW] -> bf16 channel-last [2][HW][64].
// ---------------------------------------------------------------------------
struct ToBfArgs {
  const float* src[9];
  u16* dst[9];
  int hw[9];
};

__global__ void k_tobf_all(ToBfArgs a)
{
  const int seg = blockIdx.y;
  const int hw = a.hw[seg];
  const int total = 2 * hw * 8;
  int idx = blockIdx.x * TPB + threadIdx.x;
  if (idx >= total) return;
  const int g8 = idx & 7;
  int t = idx >> 3;
  const int pos = t % hw, b = t / hw;
  const float* s = a.src[seg] + ((size_t)b * 64 + g8 * 8) * hw + pos;
  u32 w0 = pk2bf(s[0], s[(size_t)hw]);
  u32 w1 = pk2bf(s[(size_t)2 * hw], s[(size_t)3 * hw]);
  u32 w2 = pk2bf(s[(size_t)4 * hw], s[(size_t)5 * hw]);
  u32 w3 = pk2bf(s[(size_t)6 * hw], s[(size_t)7 * hw]);
  *(uint4*)&a.dst[seg][((size_t)b * hw + pos) * 64 + g8 * 8] = make_uint4(w0, w1, w2, w3);
}

// ---------------------------------------------------------------------------
// 3x3 conv via MFMA bf16. INMODE: 0 = fp32 planar in1/in2; 1 = bf16 chlast
// in1/in2; 2 = bf16 chlast in1 (full-res) + in2 chlast at HALF res with fused
// bilinear up2. OUTBF: 0 = fp32 planar out; 1 = bf16 chlast out (Cout==64)
// via LDS transpose -> full-line coalesced writes.
// ---------------------------------------------------------------------------
template<int ACT, int INMODE, int OUTBF>
__global__ __launch_bounds__(TPB, 3)
void k_conv(const void* __restrict__ in1v, int c1,
            const void* __restrict__ in2v, int c2,
            const u16* __restrict__ wbuf, const float* __restrict__ bias,
            float* __restrict__ outf, u16* __restrict__ outb,
            int Cout, int Coutpad, int Hh, int Ww)
{
  __shared__ __align__(16) u16 s_mem[324 * 40 + 3 * 64 * 40];  // 20640 u16
  u16* s_act = s_mem;
  u16* s_w   = s_mem + 324 * 40;
  const int Cin = c1 + c2;
  const int nkc = Cin >> 5, nk1 = c1 >> 5;
  const int b   = blockIdx.z;
  const int cb  = blockIdx.y << 6;
  const int xt  = Ww >> 4;
  const int by0 = (blockIdx.x / xt) << 4;
  const int bx0 = (blockIdx.x % xt) << 4;
  const int tid = threadIdx.x;
  const int lx = tid & 15, slot = (tid >> 4) & 3, wv = tid >> 6;
  const int HW = Hh * Ww;

  f32x4 acc[4][4];
#pragma unroll
  for (int i = 0; i < 4; ++i)
#pragma unroll
    for (int j = 0; j < 4; ++j) acc[i][j] = (f32x4){0.f, 0.f, 0.f, 0.f};

#pragma unroll 1
  for (int kc = 0; kc < nkc; ++kc) {
    __syncthreads();
    // ---- stage activations: 18x18 positions x 32 ch ----
    if (INMODE == 0) {
      const float* f1 = (const float*)in1v;
      const float* f2 = (const float*)in2v;
      const int cbase = kc << 5;
      const float* sp = (cbase < c1) ? f1 + ((size_t)b * c1 + cbase) * HW
                                     : f2 + ((size_t)b * c2 + (cbase - c1)) * HW;
#pragma unroll 1
      for (int u = tid; u < 324; u += TPB) {
        int y = u / 18, x = u - y * 18;
        int gy = by0 - 1 + y, gx = bx0 - 1 + x;
        bool inb = ((unsigned)gy < (unsigned)Hh) & ((unsigned)gx < (unsigned)Ww);
        const float msk = inb ? 1.f : 0.f;
        const size_t poff = inb ? ((size_t)gy * Ww + gx) : 0;
        const float* s0 = sp + poff;
        u16* dp = &s_act[u * 40];
#pragma unroll
        for (int c8 = 0; c8 < 4; ++c8) {
          u32 hb[4];
#pragma unroll
          for (int j = 0; j < 4; ++j)
            hb[j] = pk2bf(s0[(size_t)(c8 * 8 + 2 * j) * HW] * msk,
                          s0[(size_t)(c8 * 8 + 2 * j + 1) * HW] * msk);
          *(uint4*)&dp[c8 * 8] = make_uint4(hb[0], hb[1], hb[2], hb[3]);
        }
      }
    } else if (INMODE == 1 || kc < nk1) {
      const u16* b1 = (const u16*)in1v;
      const u16* b2 = (const u16*)in2v;
      const u16* src; int cofs, cst;
      if (kc < nk1) { src = b1 + (size_t)b * HW * c1; cofs = kc << 5; cst = c1; }
      else          { src = b2 + (size_t)b * HW * c2; cofs = (kc - nk1) << 5; cst = c2; }
#pragma unroll 1
      for (int i = tid; i < 1296; i += TPB) {
        int u = i >> 2, q = i & 3;
        int y = u / 18, x = u - y * 18;
        int gy = by0 - 1 + y, gx = bx0 - 1 + x;
        uint4 v = make_uint4(0u, 0u, 0u, 0u);
        if ((unsigned)gy < (unsigned)Hh && (unsigned)gx < (unsigned)Ww)
          v = *(const uint4*)&src[(size_t)(gy * Ww + gx) * cst + cofs + q * 8];
        *(uint4*)&s_act[u * 40 + q * 8] = v;
      }
    } else {
      // INMODE==2, in2 half-res with fused up2
      const u16* b2 = (const u16*)in2v;
      const int hh = Hh >> 1, hw = Ww >> 1;
      const int cofs = (kc - nk1) << 5;
#pragma unroll 1
      for (int u = tid; u < 324; u += TPB) {
        int y = u / 18, x = u - y * 18;
        int gy = by0 - 1 + y, gx = bx0 - 1 + x;
        u16* dp = &s_act[u * 40];
        if ((unsigned)gy < (unsigned)Hh && (unsigned)gx < (unsigned)Ww) {
          int iy0, iy1, ix0, ix1; float wy0, wy1, wx0, wx1;
          if (gy & 1) { iy0 = gy >> 1; iy1 = min(iy0 + 1, hh - 1); wy0 = 0.75f; wy1 = 0.25f; }
          else        { iy1 = gy >> 1; iy0 = max(iy1 - 1, 0);      wy0 = 0.25f; wy1 = 0.75f; }
          if (gx & 1) { ix0 = gx >> 1; ix1 = min(ix0 + 1, hw - 1); wx0 = 0.75f; wx1 = 0.25f; }
          else        { ix1 = gx >> 1; ix0 = max(ix1 - 1, 0);      wx0 = 0.25f; wx1 = 0.75f; }
          const u16* pb = b2 + (size_t)b * hh * hw * 64 + cofs;
#pragma unroll
          for (int q = 0; q < 4; ++q) {
            const bf16x8 a00 = *(const bf16x8*)&pb[(size_t)(iy0 * hw + ix0) * 64 + q * 8];
            const bf16x8 a01 = *(const bf16x8*)&pb[(size_t)(iy0 * hw + ix1) * 64 + q * 8];
            const bf16x8 a10 = *(const bf16x8*)&pb[(size_t)(iy1 * hw + ix0) * 64 + q * 8];
            const bf16x8 a11 = *(const bf16x8*)&pb[(size_t)(iy1 * hw + ix1) * 64 + q * 8];
            u32 r[4];
#pragma unroll
            for (int j = 0; j < 4; ++j) {
              float v0 = wy0 * (wx0 * (float)a00[2 * j] + wx1 * (float)a01[2 * j])
                       + wy1 * (wx0 * (float)a10[2 * j] + wx1 * (float)a11[2 * j]);
              float v1 = wy0 * (wx0 * (float)a00[2 * j + 1] + wx1 * (float)a01[2 * j + 1])
                       + wy1 * (wx0 * (float)a10[2 * j + 1] + wx1 * (float)a11[2 * j + 1]);
              r[j] = pk2bf(v0, v1);
            }
            *(uint4*)&dp[q * 8] = make_uint4(r[0], r[1], r[2], r[3]);
          }
        } else {
#pragma unroll
          for (int q = 0; q < 4; ++q)
            *(uint4*)&dp[q * 8] = make_uint4(0u, 0u, 0u, 0u);
        }
      }
    }
#pragma unroll 1
    for (int ky = 0; ky < 3; ++ky) {
      __syncthreads();
      {
        const size_t base = ((size_t)(kc * 9 + ky * 3) * Coutpad + cb) * 40;
        const size_t tapstride = (size_t)Coutpad * 40;
#pragma unroll 1
        for (int i = tid; i < 960; i += TPB) {
          int kxl = i / 320, j = i - kxl * 320;
          const uint4 v = *(const uint4*)&wbuf[base + (size_t)kxl * tapstride + j * 8];
          *(uint4*)&s_w[kxl * 2560 + j * 8] = v;
        }
      }
      __syncthreads();
#pragma unroll
      for (int kx = 0; kx < 3; ++kx) {
        bf16x8 Af[4], Bf[4];
#pragma unroll
        for (int ct = 0; ct < 4; ++ct)
          Af[ct] = *(const bf16x8*)&s_w[(kx * 64 + ct * 16 + lx) * 40 + slot * 8];
#pragma unroll
        for (int pg = 0; pg < 4; ++pg)
          Bf[pg] = *(const bf16x8*)&s_act[((wv * 4 + pg + ky) * 18 + lx + kx) * 40 + slot * 8];
#pragma unroll
        for (int ct = 0; ct < 4; ++ct)
#pragma unroll
          for (int pg = 0; pg < 4; ++pg)
            acc[ct][pg] = __builtin_amdgcn_mfma_f32_16x16x32_bf16(Af[ct], Bf[pg], acc[ct][pg], 0, 0, 0);
      }
    }
  }
  const int ox = bx0 + lx;
  if (OUTBF) {
    // transpose through LDS -> full 128B-line coalesced chlast writes
    __syncthreads();
#pragma unroll
    for (int ct = 0; ct < 4; ++ct) {
      const int co0 = ct * 16 + slot * 4;
      const float b0 = bias[co0], b1 = bias[co0 + 1], b2 = bias[co0 + 2], b3 = bias[co0 + 3];
#pragma unroll
      for (int pg = 0; pg < 4; ++pg) {
        const int px = (wv * 4 + pg) * 16 + lx;
        *(u32*)&s_mem[px * 72 + co0]     = pk2bf(act_f<ACT>(acc[ct][pg][0] + b0),
                                                 act_f<ACT>(acc[ct][pg][1] + b1));
        *(u32*)&s_mem[px * 72 + co0 + 2] = pk2bf(act_f<ACT>(acc[ct][pg][2] + b2),
                                                 act_f<ACT>(acc[ct][pg][3] + b3));
      }
    }
    __syncthreads();
#pragma unroll
    for (int l = tid; l < 2048; l += TPB) {
      const int px = l >> 3, ch = (l & 7) * 8;
      const int row = px >> 4, col = px & 15;
      const uint4 v = *(const uint4*)&s_mem[px * 72 + ch];
      *(uint4*)&outb[(((size_t)b * HW + (size_t)(by0 + row) * Ww + bx0 + col) << 6) + ch] = v;
    }
  } else {
#pragma unroll
    for (int ct = 0; ct < 4; ++ct) {
      const int co0 = cb + ct * 16 + slot * 4;
#pragma unroll
      for (int r = 0; r < 4; ++r) {
        const int co = co0 + r;
        if (co < Cout) {
          const float bv = bias[co];
          float* op = outf + ((size_t)b * Cout + co) * HW + (size_t)(by0 + wv * 4) * Ww + ox;
#pragma unroll
          for (int pg = 0; pg < 4; ++pg)
            op[pg * Ww] = act_f<ACT>(acc[ct][pg][r] + bv);
        }
      }
    }
  }
}

// ---------------------------------------------------------------------------
// Modulated deformable 3x3 conv (dconv5 structure, chlast bf16 x input).
// 16x8 tile, 4 groups/block (blockIdx.y=2), 32ch staged. Output fp32 planar.
// ---------------------------------------------------------------------------
template<int SIGM, int ACT>
__global__ __launch_bounds__(TPB, 4)
void k_dconv8(const u16* __restrict__ x,
              const float* __restrict__ off,
              const float* __restrict__ mask, int maskC, int maskBase,
              const float* __restrict__ wgt, const float* __restrict__ bias,
              float* __restrict__ out, int Hh, int Ww)
{
  __shared__ __align__(16) u16 s_x[240 * 40];       // [12r x 20c][32ch+pad]
  __shared__ __align__(16) float s_w[4 * 9 * 64];   // [gl][k][c][o]
  __shared__ float s_b[32];
  const int b   = blockIdx.z;
  const int gs  = blockIdx.y;                       // groups gs*4..gs*4+3
  const int xt  = Ww >> 4;
  const int ty0 = (blockIdx.x / xt) << 3;
  const int tx0 = (blockIdx.x % xt) << 4;
  const int tid = threadIdx.x;
  const int HW  = Hh * Ww;

  for (int i = tid; i < 2304; i += TPB) {
    int o = i & 7, c = (i >> 3) & 7, k = (i >> 6) % 9, gl = i / 576;
    s_w[i] = wgt[(((size_t)((gs * 4 + gl) * 8 + o)) * 8 + c) * 9 + k];
  }
  if (tid < 32) s_b[tid] = bias[gs * 32 + tid];
  // stage x: 12x20 halo, 32 channels, pure uint4 copies
  {
    const u16* xb = x + (size_t)b * HW * 64 + gs * 32;
#pragma unroll 1
    for (int i = tid; i < 960; i += TPB) {
      int px = i >> 2, q = i & 3;
      int r = px / 20, cx = px - r * 20;
      int gy = ty0 - 2 + r, gx = tx0 - 2 + cx;
      uint4 v = make_uint4(0u, 0u, 0u, 0u);
      if ((unsigned)gy < (unsigned)Hh && (unsigned)gx < (unsigned)Ww)
        v = *(const uint4*)&xb[(size_t)(gy * Ww + gx) * 64 + q * 8];
      *(uint4*)&s_x[px * 40 + q * 8] = v;
    }
  }
  __syncthreads();

  const int pin = tid & 127;
  const int ghalf = tid >> 7;
  const int py_ = pin >> 4, px_ = pin & 15;
  const int gy = ty0 + py_, gx = tx0 + px_;
  const int p  = gy * Ww + gx;

#pragma unroll
  for (int j = 0; j < 2; ++j) {
    const int gl = ghalf * 2 + j;
    const int g  = gs * 4 + gl;
    const float* ob = off  + ((size_t)b * 216 + g * 18) * HW + p;
    const float* mb = mask + ((size_t)b * maskC + maskBase + g * 9) * HW + p;
    const u16*   xg = x    + (size_t)b * HW * 64 + g * 8;
    float*       og = out  + ((size_t)b * 64 + g * 8) * HW + p;
    const float* wg = &s_w[gl * 9 * 64];

    float acc[8];
#pragma unroll
    for (int o = 0; o < 8; ++o) acc[o] = s_b[gl * 8 + o];

#pragma unroll
    for (int k = 0; k < 9; ++k) {
      const float oyk = ob[(size_t)(2 * k) * HW];
      const float oxk = ob[(size_t)(2 * k + 1) * HW];
      float m = mb[(size_t)k * HW];
      if (SIGM) m = 1.f / (1.f + expf(-m));
      const float py = (float)(gy + k / 3 - 1) + oyk;
      const float px = (float)(gx + k % 3 - 1) + oxk;
      const float y0f = floorf(py), x0f = floorf(px);
      const float fy = py - y0f, fx = px - x0f;
      const int y0 = (int)y0f, x0 = (int)x0f;
      const int y1 = y0 + 1, x1 = x0 + 1;
      const float vy0 = (y0 >= 0 && y0 < Hh) ? 1.f : 0.f;
      const float vy1 = (y1 >= 0 && y1 < Hh) ? 1.f : 0.f;
      const float vx0 = (x0 >= 0 && x0 < Ww) ? 1.f : 0.f;
      const float vx1 = (x1 >= 0 && x1 < Ww) ? 1.f : 0.f;
      const float w00 = (1.f - fy) * (1.f - fx) * vy0 * vx0 * m;
      const float w01 = (1.f - fy) * fx * vy0 * vx1 * m;
      const float w10 = fy * (1.f - fx) * vy1 * vx0 * m;
      const float w11 = fy * fx * vy1 * vx1 * m;
      const float* wk = &wg[k * 64];
      const int ly = y0 - ty0 + 2, lxw = x0 - tx0 + 2;
      if ((unsigned)ly < 11u && (unsigned)lxw < 19u) {
        const u16* base = &s_x[(ly * 20 + lxw) * 40 + gl * 8];
        const bf16x8 c00 = *(const bf16x8*)base;
        const bf16x8 c01 = *(const bf16x8*)(base + 40);
        const bf16x8 c10 = *(const bf16x8*)(base + 800);
        const bf16x8 c11 = *(const bf16x8*)(base + 840);
#pragma unroll
        for (int c = 0; c < 8; ++c) {
          const float s = w00 * (float)c00[c] + w01 * (float)c01[c]
                        + w10 * (float)c10[c] + w11 * (float)c11[c];
          const float4 wv0 = *(const float4*)&wk[c * 8];
          const float4 wv1 = *(const float4*)&wk[c * 8 + 4];
          acc[0] = fmaf(s, wv0.x, acc[0]); acc[1] = fmaf(s, wv0.y, acc[1]);
          acc[2] = fmaf(s, wv0.z, acc[2]); acc[3] = fmaf(s, wv0.w, acc[3]);
          acc[4] = fmaf(s, wv1.x, acc[4]); acc[5] = fmaf(s, wv1.y, acc[5]);
          acc[6] = fmaf(s, wv1.z, acc[6]); acc[7] = fmaf(s, wv1.w, acc[7]);
        }
      } else {
        const int cy0 = min(max(y0, 0), Hh - 1), cy1 = min(max(y1, 0), Hh - 1);
        const int cx0 = min(max(x0, 0), Ww - 1), cx1 = min(max(x1, 0), Ww - 1);
        const bf16x8 c00 = *(const bf16x8*)&xg[(size_t)(cy0 * Ww + cx0) * 64];
        const bf16x8 c01 = *(const bf16x8*)&xg[(size_t)(cy0 * Ww + cx1) * 64];
        const bf16x8 c10 = *(const bf16x8*)&xg[(size_t)(cy1 * Ww + cx0) * 64];
        const bf16x8 c11 = *(const bf16x8*)&xg[(size_t)(cy1 * Ww + cx1) * 64];
#pragma unroll
        for (int c = 0; c < 8; ++c) {
          const float s = w00 * (float)c00[c] + w01 * (float)c01[c]
                        + w10 * (float)c10[c] + w11 * (float)c11[c];
          const float4 wv0 = *(const float4*)&wk[c * 8];
          const float4 wv1 = *(const float4*)&wk[c * 8 + 4];
          acc[0] = fmaf(s, wv0.x, acc[0]); acc[1] = fmaf(s, wv0.y, acc[1]);
          acc[2] = fmaf(s, wv0.z, acc[2]); acc[3] = fmaf(s, wv0.w, acc[3]);
          acc[4] = fmaf(s, wv1.x, acc[4]); acc[5] = fmaf(s, wv1.y, acc[5]);
          acc[6] = fmaf(s, wv1.z, acc[6]); acc[7] = fmaf(s, wv1.w, acc[7]);
        }
      }
    }
#pragma unroll
    for (int o = 0; o < 8; ++o) og[(size_t)o * HW] = act_f<ACT>(acc[o]);
  }
}

// ---------------------------------------------------------------------------
// Bilinear 2x upsample, fp32 planar (dn paths only)
// ---------------------------------------------------------------------------
__global__ void k_up2(const float* __restrict__ in, float* __restrict__ out,
                      int planes, int h, int w)
{
  const int ow = 2 * w, oh = 2 * h;
  const int total = planes * oh * ow;
  int idx = blockIdx.x * TPB + threadIdx.x;
  if (idx >= total) return;
  const int pl = idx / (oh * ow);
  const int rem = idx - pl * (oh * ow);
  const int oyj = rem / ow, oxj = rem - oyj * ow;
  int iy0, iy1, ix0, ix1; float wy0, wy1, wx0, wx1;
  if (oyj & 1) { iy0 = oyj >> 1; iy1 = min(iy0 + 1, h - 1); wy0 = 0.75f; wy1 = 0.25f; }
  else         { iy1 = oyj >> 1; iy0 = max(iy1 - 1, 0);     wy0 = 0.25f; wy1 = 0.75f; }
  if (oxj & 1) { ix0 = oxj >> 1; ix1 = min(ix0 + 1, w - 1); wx0 = 0.75f; wx1 = 0.25f; }
  else         { ix1 = oxj >> 1; ix0 = max(ix1 - 1, 0);     wx0 = 0.25f; wx1 = 0.75f; }
  const float* pp = in + (size_t)pl * h * w;
  out[idx] = wy0 * (wx0 * pp[iy0 * w + ix0] + wx1 * pp[iy0 * w + ix1])
           + wy1 * (wx0 * pp[iy1 * w + ix0] + wx1 * pp[iy1 * w + ix1]);
}

// ---------------------------------------------------------------------------
// host-side helpers (B = 2 fixed)
// mode: 0 fp32-in, 1 chlast-in, 2 chlast-in + in2 up2-fused
// ---------------------------------------------------------------------------
static void conv3(hipStream_t st, const void* in1, int c1, const void* in2, int c2,
                  const u16* wbuf, const float* bias, float* outf, u16* outb,
                  int Cout, int h, int wd, int act, int mode)
{
  int cocols = (Cout + 63) / 64, Coutpad = cocols * 64;
  dim3 grid((h / 16) * (wd / 16), cocols, 2);
  if (outb) {
    if (mode == 2)      k_conv<1,2,1><<<grid, TPB, 0, st>>>(in1, c1, in2, c2, wbuf, bias, nullptr, outb, Cout, Coutpad, h, wd);
    else if (mode == 1) k_conv<1,1,1><<<grid, TPB, 0, st>>>(in1, c1, in2, c2, wbuf, bias, nullptr, outb, Cout, Coutpad, h, wd);
    else                k_conv<0,0,1><<<grid, TPB, 0, st>>>(in1, c1, in2, c2, wbuf, bias, nullptr, outb, Cout, Coutpad, h, wd);
  } else {
    if (mode == 0)      k_conv<1,0,0><<<grid, TPB, 0, st>>>(in1, c1, in2, c2, wbuf, bias, outf, nullptr, Cout, Coutpad, h, wd);
    else if (act == 0)  k_conv<0,1,0><<<grid, TPB, 0, st>>>(in1, c1, in2, c2, wbuf, bias, outf, nullptr, Cout, Coutpad, h, wd);
    else                k_conv<2,1,0><<<grid, TPB, 0, st>>>(in1, c1, in2, c2, wbuf, bias, outf, nullptr, Cout, Coutpad, h, wd);
  }
}

static void dconv(hipStream_t st, const u16* x, const float* om, const float* mask,
                  int maskC, int maskBase, const float* w, const float* b, float* out,
                  int h, int wd, int sigm, int act)
{
  dim3 grid((h / 8) * (wd / 16), 2, 2);
  if (sigm) {
    if (act) k_dconv8<1,1><<<grid, TPB, 0, st>>>(x, om, mask, maskC, maskBase, w, b, out, h, wd);
    else     k_dconv8<1,0><<<grid, TPB, 0, st>>>(x, om, mask, maskC, maskBase, w, b, out, h, wd);
  } else     k_dconv8<0,0><<<grid, TPB, 0, st>>>(x, om, mask, maskC, maskBase, w, b, out, h, wd);
}

static void up2f(hipStream_t st, const float* in, float* out, int h, int w)
{
  int total = 128 * 4 * h * w;
  k_up2<<<(total + TPB - 1) / TPB, TPB, 0, st>>>(in, out, 128, h, w);
}

extern "C" void kernel_launch(void* const* d_in, const int* in_sizes, int n_in,
                              void* d_out, int out_size, void* d_ws, size_t ws_size,
                              hipStream_t stream)
{
  const float* const* in = (const float* const*)d_in;

  const int HW0 = 192 * 192, HW1 = 96 * 96, HW2 = 48 * 48;
  const size_t N0 = (size_t)2 * HW0 * 64, N1 = (size_t)2 * HW1 * 64, N2 = (size_t)2 * HW2 * 64;

  u16* p = (u16*)d_ws;
  u16* rf0b  = p; p += N0;
  u16* nrf0b = p; p += N0;
  u16* swf0b = p; p += N0;
  u16* nrf1b = p; p += N1;
  u16* rf1b  = p; p += N1;
  u16* swf1b = p; p += N1;
  u16* nrf2b = p; p += N2;
  u16* rf2b  = p; p += N2;
  u16* swf2b = p; p += N2;
  u16* Abf   = p; p += N0;
  u16* Bbf   = p; p += N0;
  u16* of1bf = p; p += N1;
  u16* of2bf = p; p += N2;
  p = (u16*)(((uintptr_t)p + 15) & ~(uintptr_t)15);
  float* OM   = (float*)p;
  float* EM   = OM + (size_t)2 * 216 * HW0;
  float* dn1f = EM + (size_t)2 * 72 * HW0;
  float* dn2f = dn1f + (size_t)2 * 64 * HW1;
  u16*   wp   = (u16*)(dn2f + (size_t)2 * 64 * HW2);
  // liveness aliases
  float* Uf0  = (float*)nrf0b;                      // up2(dn1) @192 (after xd0)
  float* Uf1  = (float*)nrf1b;                      // up2(dn2) @96 (after xd1)
  float* xd0f = EM;                                 // after sh0
  float* xd1f = EM + (size_t)2 * 72 * HW1 + 1024;   // after sh1 (level-1 EM extent)
  u16*   Cbf  = rf0b;                               // cas2 out (after cas1)

  float* dout = (float*)d_out;
  const size_t L0 = (size_t)2 * 64 * HW0;
  float* out0 = dout;
  float* sh0  = dout + L0;
  float* sh1  = sh0  + L0;
  float* sh2  = sh1  + L0 / 4;

  // ---- input conversion ----
  {
    ToBfArgs ta;
    const float* srcs[9] = {in[1], in[0], in[2], in[3], in[4], in[5], in[6], in[7], in[8]};
    u16* dsts[9] = {rf0b, nrf0b, swf0b, nrf1b, rf1b, swf1b, nrf2b, rf2b, swf2b};
    const int hws[9] = {HW0, HW0, HW0, HW1, HW1, HW1, HW2, HW2, HW2};
    for (int i = 0; i < 9; ++i) { ta.src[i] = srcs[i]; ta.dst[i] = dsts[i]; ta.hw[i] = hws[i]; }
    int maxtot = 2 * HW0 * 8;
    k_tobf_all<<<dim3((maxtot + TPB - 1) / TPB, 9), TPB, 0, stream>>>(ta);
  }

  // ---- weight prep ----
  struct { int arg, cin, cout; } plist[22] = {
    {9,128,64},{11,64,64},{13,64,216},{15,128,64},{17,64,72},
    {21,128,64},{23,64,64},{25,64,216},{27,128,64},{29,64,72},
    {33,128,64},{35,64,64},{37,64,216},{39,128,64},{41,64,72},
    {45,128,64},{47,128,64},{49,128,64},{51,128,64},
    {53,128,64},{55,64,64},{57,64,216}};
  WPrepArgs wa;
  u16* wptr[22];
  int maxtot = 0;
  for (int i = 0; i < 22; ++i) {
    int cin = plist[i].cin, cout = plist[i].cout;
    int cpad = ((cout + 63) / 64) * 64;
    int tot = (cin / 32) * 9 * cpad * 40;
    wa.src[i] = in[plist[i].arg]; wa.dst[i] = wp;
    wa.cin[i] = cin; wa.cout[i] = cout; wa.coutpad[i] = cpad; wa.total[i] = tot;
    wptr[i] = wp; wp += tot;
    if (tot > maxtot) maxtot = tot;
  }
  k_wprep_all<<<dim3((maxtot + TPB - 1) / TPB, 22), TPB, 0, stream>>>(wa);

  u16* w_ocf0 = wptr[0];  u16* w_ocl0 = wptr[1];  u16* w_com0 = wptr[2];
  u16* w_em10 = wptr[3];  u16* w_em20 = wptr[4];
  u16* w_ocf1 = wptr[5];  u16* w_ocl1 = wptr[6];  u16* w_com1 = wptr[7];
  u16* w_em11 = wptr[8];  u16* w_em21 = wptr[9];
  u16* w_ocf2 = wptr[10]; u16* w_ocl2 = wptr[11]; u16* w_com2 = wptr[12];
  u16* w_em12 = wptr[13]; u16* w_em22 = wptr[14];
  u16* w_occ0 = wptr[15]; u16* w_fcc0 = wptr[16];
  u16* w_occ1 = wptr[17]; u16* w_fcc1 = wptr[18];
  u16* w_cas1 = wptr[19]; u16* w_cas2 = wptr[20]; u16* w_casc = wptr[21];

  // ----- level 2 (48x48) -----
  const int h2 = 48;
  conv3(stream, nrf2b, 64, rf2b, 64,  w_ocf2, in[34], nullptr, Abf,   64,  h2, h2, 1, 1);
  conv3(stream, Abf,   64, 0,   0,    w_ocl2, in[36], nullptr, of2bf, 64,  h2, h2, 1, 1);
  conv3(stream, swf2b, 64, 0,   0,    w_com2, in[38], OM, nullptr,   216,  h2, h2, 0, 1);
  conv3(stream, of2bf, 64, swf2b, 64, w_em12, in[40], nullptr, Abf,   64,  h2, h2, 1, 1);
  conv3(stream, Abf,   64, 0,   0,    w_em22, in[42], EM, nullptr,    72,  h2, h2, 2, 1);
  dconv(stream, of2bf, OM, EM,  72, 0,   in[43], in[44], sh2,  h2, h2, 0, 0);
  dconv(stream, nrf2b, OM, OM, 216, 144, in[43], in[44], dn2f, h2, h2, 1, 1);

  // ----- level 1 (96x96) -----
  const int h1 = 96;
  conv3(stream, nrf1b, 64, rf1b, 64,  w_ocf1, in[22], nullptr, Abf,   64, h1, h1, 1, 1);
  conv3(stream, Abf,   64, of2bf, 64, w_occ1, in[50], nullptr, Bbf,   64, h1, h1, 1, 2);
  conv3(stream, Bbf,   64, 0,   0,    w_ocl1, in[24], nullptr, of1bf, 64, h1, h1, 1, 1);
  conv3(stream, swf1b, 64, 0,   0,    w_com1, in[26], OM, nullptr,  216,  h1, h1, 0, 1);
  conv3(stream, of1bf, 64, swf1b, 64, w_em11, in[28], nullptr, Abf,   64, h1, h1, 1, 1);
  conv3(stream, Abf,   64, 0,   0,    w_em21, in[30], EM, nullptr,   72,  h1, h1, 2, 1);
  dconv(stream, of1bf, OM, EM,  72, 0,   in[31], in[32], sh1,  h1, h1, 0, 0);
  dconv(stream, nrf1b, OM, OM, 216, 144, in[31], in[32], xd1f, h1, h1, 1, 0);
  up2f(stream, dn2f, Uf1, h2, h2);
  conv3(stream, xd1f, 64, Uf1, 64,    w_fcc1, in[52], dn1f, nullptr, 64, h1, h1, 1, 0);

  // ----- level 0 (192x192) -----
  const int h0 = 192;
  conv3(stream, nrf0b, 64, rf0b, 64,  w_ocf0, in[10], nullptr, Abf, 64, h0, h0, 1, 1);
  conv3(stream, Abf,   64, of1bf, 64, w_occ0, in[46], nullptr, Bbf, 64, h0, h0, 1, 2);
  conv3(stream, Bbf,   64, 0,   0,    w_ocl0, in[12], nullptr, Abf, 64, h0, h0, 1, 1);  // of0
  conv3(stream, swf0b, 64, 0,   0,    w_com0, in[14], OM, nullptr, 216, h0, h0, 0, 1);
  conv3(stream, Abf,   64, swf0b, 64, w_em10, in[16], nullptr, Bbf, 64, h0, h0, 1, 1);
  conv3(stream, Bbf,   64, 0,   0,    w_em20, in[18], EM, nullptr,  72, h0, h0, 2, 1);
  dconv(stream, Abf,   OM, EM,  72, 0,   in[19], in[20], sh0,  h0, h0, 0, 0);
  dconv(stream, nrf0b, OM, OM, 216, 144, in[19], in[20], xd0f, h0, h0, 1, 0);
  up2f(stream, dn1f, Uf0, h1, h1);
  conv3(stream, xd0f, 64, Uf0, 64,    w_fcc0, in[48], nullptr, Abf, 64, h0, h0, 0, 0);  // dn0
  conv3(stream, Abf,   64, rf0b, 64,  w_cas1, in[54], nullptr, Bbf, 64, h0, h0, 1, 1);
  conv3(stream, Bbf,   64, 0,   0,    w_cas2, in[56], nullptr, Cbf, 64, h0, h0, 1, 1);
  conv3(stream, Cbf,   64, 0,   0,    w_casc, in[58], OM, nullptr, 216, h0, h0, 0, 1);
  dconv(stream, Abf,   OM, OM, 216, 144, in[59], in[60], out0, h0, h0, 1, 1);
}

// Round 12
// 1110.176 us; speedup vs baseline: 3.6562x; 3.6562x over previous
//
#include <hip/hip_runtime.h>
#include <cstddef>
#include <cstdint>

#define TPB 256

typedef unsigned int u32;
typedef unsigned short u16;
typedef __bf16 bf16x8 __attribute__((ext_vector_type(8)));
typedef float f32x4 __attribute__((ext_vector_type(4)));

template<int ACT>
__device__ __forceinline__ float act_f(float v) {
  if (ACT == 1) return v >= 0.f ? v : 0.1f * v;          // lrelu
  if (ACT == 2) return 1.f / (1.f + expf(-v));           // sigmoid
  return v;
}

__device__ __forceinline__ u16 f2bf(float f) {
  __bf16 h = (__bf16)f;
  return __builtin_bit_cast(u16, h);
}
__device__ __forceinline__ u32 pk2bf(float a, float b) {
  return (u32)f2bf(a) | ((u32)f2bf(b) << 16);
}

// ---------------------------------------------------------------------------
// Weight prep (one launch, 22 convs): fp32 [Cout][Cin][3][3] -> bf16
// [kc][tap][co(pad)][40].
// ---------------------------------------------------------------------------
struct WPrepArgs {
  const float* src[22];
  u16* dst[22];
  int cin[22], cout[22], coutpad[22], total[22];
};

__global__ void k_wprep_all(WPrepArgs a)
{
  const int seg = blockIdx.y;
  const int idx = blockIdx.x * TPB + threadIdx.x;
  if (idx >= a.total[seg]) return;
  const int Cin = a.cin[seg], Cout = a.cout[seg], Coutpad = a.coutpad[seg];
  int kk = idx % 40; int t = idx / 40;
  int co = t % Coutpad; t /= Coutpad;
  int tap = t % 9; int kc = t / 9;
  u16 v = 0;
  if (kk < 32 && co < Cout)
    v = f2bf(a.src[seg][((size_t)co * Cin + kc * 32 + kk) * 9 + tap]);
  a.dst[seg][idx] = v;
}

// ---------------------------------------------------------------------------
// Input prep: fp32 planar [2][64][HW] -> bf16 channel-last [2][HW][64].
// ---------------------------------------------------------------------------
struct ToBfArgs {
  const float* src[9];
  u16* dst[9];
  int hw[9];
};

__global__ void k_tobf_all(ToBfArgs a)
{
  const int seg = blockIdx.y;
  const int hw = a.hw[seg];
  const int total = 2 * hw * 8;
  int idx = blockIdx.x * TPB + threadIdx.x;
  if (idx >= total) return;
  const int g8 = idx & 7;
  int t = idx >> 3;
  const int pos = t % hw, b = t / hw;
  const float* s = a.src[seg] + ((size_t)b * 64 + g8 * 8) * hw + pos;
  u32 w0 = pk2bf(s[0], s[(size_t)hw]);
  u32 w1 = pk2bf(s[(size_t)2 * hw], s[(size_t)3 * hw]);
  u32 w2 = pk2bf(s[(size_t)4 * hw], s[(size_t)5 * hw]);
  u32 w3 = pk2bf(s[(size_t)6 * hw], s[(size_t)7 * hw]);
  *(uint4*)&a.dst[seg][((size_t)b * hw + pos) * 64 + g8 * 8] = make_uint4(w0, w1, w2, w3);
}

// ---------------------------------------------------------------------------
// 3x3 conv via MFMA bf16. Per-input mode M1/M2: 0 = fp32 planar, 1 = bf16
// channel-last [B][HW][C]. OUTBF: 0 = fp32 planar out; 1 = bf16 chlast out
// (Cout==64) via LDS transpose -> full-line coalesced writes.
// ---------------------------------------------------------------------------
template<int ACT, int M1, int M2, int OUTBF>
__global__ __launch_bounds__(TPB, 3)
void k_conv(const void* __restrict__ in1v, int c1,
            const void* __restrict__ in2v, int c2,
            const u16* __restrict__ wbuf, const float* __restrict__ bias,
            float* __restrict__ outf, u16* __restrict__ outb,
            int Cout, int Coutpad, int Hh, int Ww)
{
  __shared__ __align__(16) u16 s_mem[324 * 40 + 3 * 64 * 40];
  u16* s_act = s_mem;
  u16* s_w   = s_mem + 324 * 40;
  const int Cin = c1 + c2;
  const int nkc = Cin >> 5, nk1 = c1 >> 5;
  const int b   = blockIdx.z;
  const int cb  = blockIdx.y << 6;
  const int xt  = Ww >> 4;
  const int by0 = (blockIdx.x / xt) << 4;
  const int bx0 = (blockIdx.x % xt) << 4;
  const int tid = threadIdx.x;
  const int lx = tid & 15, slot = (tid >> 4) & 3, wv = tid >> 6;
  const int HW = Hh * Ww;

  f32x4 acc[4][4];
#pragma unroll
  for (int i = 0; i < 4; ++i)
#pragma unroll
    for (int j = 0; j < 4; ++j) acc[i][j] = (f32x4){0.f, 0.f, 0.f, 0.f};

#pragma unroll 1
  for (int kc = 0; kc < nkc; ++kc) {
    __syncthreads();
    const bool use1 = kc < nk1;
    const int mode = use1 ? M1 : M2;
    if (mode == 0) {
      // fp32 planar staging + cvt
      const float* sp = use1
        ? (const float*)in1v + ((size_t)b * c1 + (kc << 5)) * HW
        : (const float*)in2v + ((size_t)b * c2 + ((kc - nk1) << 5)) * HW;
#pragma unroll 1
      for (int u = tid; u < 324; u += TPB) {
        int y = u / 18, x = u - y * 18;
        int gy = by0 - 1 + y, gx = bx0 - 1 + x;
        bool inb = ((unsigned)gy < (unsigned)Hh) & ((unsigned)gx < (unsigned)Ww);
        const float msk = inb ? 1.f : 0.f;
        const size_t poff = inb ? ((size_t)gy * Ww + gx) : 0;
        const float* s0 = sp + poff;
        u16* dp = &s_act[u * 40];
#pragma unroll
        for (int c8 = 0; c8 < 4; ++c8) {
          u32 hb[4];
#pragma unroll
          for (int j = 0; j < 4; ++j)
            hb[j] = pk2bf(s0[(size_t)(c8 * 8 + 2 * j) * HW] * msk,
                          s0[(size_t)(c8 * 8 + 2 * j + 1) * HW] * msk);
          *(uint4*)&dp[c8 * 8] = make_uint4(hb[0], hb[1], hb[2], hb[3]);
        }
      }
    } else {
      // chlast staging: pure uint4 copies
      const u16* src; int cofs, cst;
      if (use1) { src = (const u16*)in1v + (size_t)b * HW * c1; cofs = kc << 5; cst = c1; }
      else      { src = (const u16*)in2v + (size_t)b * HW * c2; cofs = (kc - nk1) << 5; cst = c2; }
#pragma unroll 1
      for (int i = tid; i < 1296; i += TPB) {
        int u = i >> 2, q = i & 3;
        int y = u / 18, x = u - y * 18;
        int gy = by0 - 1 + y, gx = bx0 - 1 + x;
        uint4 v = make_uint4(0u, 0u, 0u, 0u);
        if ((unsigned)gy < (unsigned)Hh && (unsigned)gx < (unsigned)Ww)
          v = *(const uint4*)&src[(size_t)(gy * Ww + gx) * cst + cofs + q * 8];
        *(uint4*)&s_act[u * 40 + q * 8] = v;
      }
    }
#pragma unroll 1
    for (int ky = 0; ky < 3; ++ky) {
      __syncthreads();
      {
        const size_t base = ((size_t)(kc * 9 + ky * 3) * Coutpad + cb) * 40;
        const size_t tapstride = (size_t)Coutpad * 40;
#pragma unroll 1
        for (int i = tid; i < 960; i += TPB) {
          int kxl = i / 320, j = i - kxl * 320;
          const uint4 v = *(const uint4*)&wbuf[base + (size_t)kxl * tapstride + j * 8];
          *(uint4*)&s_w[kxl * 2560 + j * 8] = v;
        }
      }
      __syncthreads();
#pragma unroll
      for (int kx = 0; kx < 3; ++kx) {
        bf16x8 Af[4], Bf[4];
#pragma unroll
        for (int ct = 0; ct < 4; ++ct)
          Af[ct] = *(const bf16x8*)&s_w[(kx * 64 + ct * 16 + lx) * 40 + slot * 8];
#pragma unroll
        for (int pg = 0; pg < 4; ++pg)
          Bf[pg] = *(const bf16x8*)&s_act[((wv * 4 + pg + ky) * 18 + lx + kx) * 40 + slot * 8];
#pragma unroll
        for (int ct = 0; ct < 4; ++ct)
#pragma unroll
          for (int pg = 0; pg < 4; ++pg)
            acc[ct][pg] = __builtin_amdgcn_mfma_f32_16x16x32_bf16(Af[ct], Bf[pg], acc[ct][pg], 0, 0, 0);
      }
    }
  }
  const int ox = bx0 + lx;
  if (OUTBF) {
    __syncthreads();
#pragma unroll
    for (int ct = 0; ct < 4; ++ct) {
      const int co0 = ct * 16 + slot * 4;
      const float b0 = bias[co0], b1 = bias[co0 + 1], b2 = bias[co0 + 2], b3 = bias[co0 + 3];
#pragma unroll
      for (int pg = 0; pg < 4; ++pg) {
        const int px = (wv * 4 + pg) * 16 + lx;
        *(u32*)&s_mem[px * 72 + co0]     = pk2bf(act_f<ACT>(acc[ct][pg][0] + b0),
                                                 act_f<ACT>(acc[ct][pg][1] + b1));
        *(u32*)&s_mem[px * 72 + co0 + 2] = pk2bf(act_f<ACT>(acc[ct][pg][2] + b2),
                                                 act_f<ACT>(acc[ct][pg][3] + b3));
      }
    }
    __syncthreads();
#pragma unroll 1
    for (int l = tid; l < 2048; l += TPB) {
      const int px = l >> 3, ch = (l & 7) * 8;
      const int row = px >> 4, col = px & 15;
      const uint4 v = *(const uint4*)&s_mem[px * 72 + ch];
      *(uint4*)&outb[(((size_t)b * HW + (size_t)(by0 + row) * Ww + bx0 + col) << 6) + ch] = v;
    }
  } else {
#pragma unroll
    for (int ct = 0; ct < 4; ++ct) {
      const int co0 = cb + ct * 16 + slot * 4;
#pragma unroll
      for (int r = 0; r < 4; ++r) {
        const int co = co0 + r;
        if (co < Cout) {
          const float bv = bias[co];
          float* op = outf + ((size_t)b * Cout + co) * HW + (size_t)(by0 + wv * 4) * Ww + ox;
#pragma unroll
          for (int pg = 0; pg < 4; ++pg)
            op[pg * Ww] = act_f<ACT>(acc[ct][pg][r] + bv);
        }
      }
    }
  }
}

// ---------------------------------------------------------------------------
// Modulated deformable 3x3 conv, dconv5 (verbatim round-7 structure, proven
// 80us @192^2). x fp32 planar; 16x8 tile, 4 groups/block; x staged to LDS as
// bf16 channel-last [240 px][40]; corner = one ds_read_b128; fallback =
// scalar fp32 planar global loads. Output fp32 planar.
// ---------------------------------------------------------------------------
template<int SIGM, int ACT>
__global__ __launch_bounds__(TPB, 4)
void k_dconv5(const float* __restrict__ x,
              const float* __restrict__ off,
              const float* __restrict__ mask, int maskC, int maskBase,
              const float* __restrict__ wgt, const float* __restrict__ bias,
              float* __restrict__ out, int Hh, int Ww)
{
  __shared__ __align__(16) u16 s_x[240][40];        // [12 rows x 20 cols][32ch+pad]
  __shared__ __align__(16) float s_w[4 * 9 * 64];   // [gl][k][c][o]
  __shared__ float s_b[32];
  const int b   = blockIdx.z;
  const int gs  = blockIdx.y;                       // group half: gs*4..gs*4+3
  const int xt  = Ww >> 4;
  const int ty0 = (blockIdx.x / xt) << 3;
  const int tx0 = (blockIdx.x % xt) << 4;
  const int tid = threadIdx.x;
  const int HW  = Hh * Ww;

  for (int i = tid; i < 2304; i += TPB) {
    int o = i & 7, c = (i >> 3) & 7, k = (i >> 6) % 9, gl = i / 576;
    s_w[i] = wgt[(((size_t)((gs * 4 + gl) * 8 + o)) * 8 + c) * 9 + k];
  }
  if (tid < 32) s_b[tid] = bias[gs * 32 + tid];
  {
    const float* xb = x + ((size_t)b * 64 + gs * 32) * HW;
#pragma unroll 1
    for (int i = tid; i < 240 * 32; i += TPB) {
      int c = i / 240, px = i - c * 240;
      int r = px / 20, cx = px - r * 20;
      int gy = ty0 - 2 + r, gx = tx0 - 2 + cx;
      float v = 0.f;
      if ((unsigned)gy < (unsigned)Hh && (unsigned)gx < (unsigned)Ww)
        v = xb[(size_t)c * HW + gy * Ww + gx];
      s_x[px][c] = f2bf(v);
    }
  }
  __syncthreads();

  const int pin = tid & 127;
  const int ghalf = tid >> 7;
  const int py_ = pin >> 4, px_ = pin & 15;
  const int gy = ty0 + py_, gx = tx0 + px_;
  const int p  = gy * Ww + gx;

#pragma unroll
  for (int j = 0; j < 2; ++j) {
    const int gl = ghalf * 2 + j;
    const int g  = gs * 4 + gl;
    const float* ob = off  + ((size_t)b * 216 + g * 18) * HW + p;
    const float* mb = mask + ((size_t)b * maskC + maskBase + g * 9) * HW + p;
    const float* xg = x    + ((size_t)b * 64 + g * 8) * HW;
    float*       og = out  + ((size_t)b * 64 + g * 8) * HW + p;
    const float* wg = &s_w[gl * 9 * 64];

    float acc[8];
#pragma unroll
    for (int o = 0; o < 8; ++o) acc[o] = s_b[gl * 8 + o];

#pragma unroll
    for (int k = 0; k < 9; ++k) {
      const float oyk = ob[(size_t)(2 * k) * HW];
      const float oxk = ob[(size_t)(2 * k + 1) * HW];
      float m = mb[(size_t)k * HW];
      if (SIGM) m = 1.f / (1.f + expf(-m));
      const float py = (float)(gy + k / 3 - 1) + oyk;
      const float px = (float)(gx + k % 3 - 1) + oxk;
      const float y0f = floorf(py), x0f = floorf(px);
      const float fy = py - y0f, fx = px - x0f;
      const int y0 = (int)y0f, x0 = (int)x0f;
      const int y1 = y0 + 1, x1 = x0 + 1;
      const float vy0 = (y0 >= 0 && y0 < Hh) ? 1.f : 0.f;
      const float vy1 = (y1 >= 0 && y1 < Hh) ? 1.f : 0.f;
      const float vx0 = (x0 >= 0 && x0 < Ww) ? 1.f : 0.f;
      const float vx1 = (x1 >= 0 && x1 < Ww) ? 1.f : 0.f;
      const float w00 = (1.f - fy) * (1.f - fx) * vy0 * vx0 * m;
      const float w01 = (1.f - fy) * fx * vy0 * vx1 * m;
      const float w10 = fy * (1.f - fx) * vy1 * vx0 * m;
      const float w11 = fy * fx * vy1 * vx1 * m;
      const float* wk = &wg[k * 64];
      const int ly = y0 - ty0 + 2, lxw = x0 - tx0 + 2;
      if ((unsigned)ly < 11u && (unsigned)lxw < 19u) {
        const u16* base = &s_x[ly * 20 + lxw][gl * 8];
        const bf16x8 c00 = *(const bf16x8*)base;
        const bf16x8 c01 = *(const bf16x8*)(base + 40);
        const bf16x8 c10 = *(const bf16x8*)(base + 800);
        const bf16x8 c11 = *(const bf16x8*)(base + 840);
#pragma unroll
        for (int c = 0; c < 8; ++c) {
          const float s = w00 * (float)c00[c] + w01 * (float)c01[c]
                        + w10 * (float)c10[c] + w11 * (float)c11[c];
          const float4 wv0 = *(const float4*)&wk[c * 8];
          const float4 wv1 = *(const float4*)&wk[c * 8 + 4];
          acc[0] = fmaf(s, wv0.x, acc[0]); acc[1] = fmaf(s, wv0.y, acc[1]);
          acc[2] = fmaf(s, wv0.z, acc[2]); acc[3] = fmaf(s, wv0.w, acc[3]);
          acc[4] = fmaf(s, wv1.x, acc[4]); acc[5] = fmaf(s, wv1.y, acc[5]);
          acc[6] = fmaf(s, wv1.z, acc[6]); acc[7] = fmaf(s, wv1.w, acc[7]);
        }
      } else {
        const int cy0 = min(max(y0, 0), Hh - 1), cy1 = min(max(y1, 0), Hh - 1);
        const int cx0 = min(max(x0, 0), Ww - 1), cx1 = min(max(x1, 0), Ww - 1);
        const int i00 = cy0 * Ww + cx0, i01 = cy0 * Ww + cx1;
        const int i10 = cy1 * Ww + cx0, i11 = cy1 * Ww + cx1;
#pragma unroll
        for (int c = 0; c < 8; ++c) {
          const float* pl = xg + (size_t)c * HW;
          const float s = w00 * pl[i00] + w01 * pl[i01] + w10 * pl[i10] + w11 * pl[i11];
          const float4 wv0 = *(const float4*)&wk[c * 8];
          const float4 wv1 = *(const float4*)&wk[c * 8 + 4];
          acc[0] = fmaf(s, wv0.x, acc[0]); acc[1] = fmaf(s, wv0.y, acc[1]);
          acc[2] = fmaf(s, wv0.z, acc[2]); acc[3] = fmaf(s, wv0.w, acc[3]);
          acc[4] = fmaf(s, wv1.x, acc[4]); acc[5] = fmaf(s, wv1.y, acc[5]);
          acc[6] = fmaf(s, wv1.z, acc[6]); acc[7] = fmaf(s, wv1.w, acc[7]);
        }
      }
    }
#pragma unroll
    for (int o = 0; o < 8; ++o) og[(size_t)o * HW] = act_f<ACT>(acc[o]);
  }
}

// ---------------------------------------------------------------------------
// Bilinear 2x upsample, fp32 planar, 128 planes
// ---------------------------------------------------------------------------
__global__ void k_up2(const float* __restrict__ in, float* __restrict__ out,
                      int h, int w)
{
  const int ow = 2 * w, oh = 2 * h;
  const int total = 128 * oh * ow;
  int idx = blockIdx.x * TPB + threadIdx.x;
  if (idx >= total) return;
  const int pl = idx / (oh * ow);
  const int rem = idx - pl * (oh * ow);
  const int oyj = rem / ow, oxj = rem - oyj * ow;
  int iy0, iy1, ix0, ix1; float wy0, wy1, wx0, wx1;
  if (oyj & 1) { iy0 = oyj >> 1; iy1 = min(iy0 + 1, h - 1); wy0 = 0.75f; wy1 = 0.25f; }
  else         { iy1 = oyj >> 1; iy0 = max(iy1 - 1, 0);     wy0 = 0.25f; wy1 = 0.75f; }
  if (oxj & 1) { ix0 = oxj >> 1; ix1 = min(ix0 + 1, w - 1); wx0 = 0.75f; wx1 = 0.25f; }
  else         { ix1 = oxj >> 1; ix0 = max(ix1 - 1, 0);     wx0 = 0.25f; wx1 = 0.75f; }
  const float* pp = in + (size_t)pl * h * w;
  out[idx] = wy0 * (wx0 * pp[iy0 * w + ix0] + wx1 * pp[iy0 * w + ix1])
           + wy1 * (wx0 * pp[iy1 * w + ix0] + wx1 * pp[iy1 * w + ix1]);
}

// ---------------------------------------------------------------------------
// host helpers (B = 2 fixed)
// variant: 0 ocf/cas2 (1,1,1,1) | 1 occ (1,1,0,1) | 2 ocl (1,1,1,0)
//          3 com/casc (0,1,1,0) | 4 em2 (2,1,1,0) | 5 em1/cas1 (1,0,1,1)
//          6 fcc0 (0,0,0,0)     | 7 fcc1 (1,0,0,0)
// ---------------------------------------------------------------------------
static void conv3(hipStream_t st, int variant,
                  const void* in1, int c1, const void* in2, int c2,
                  const u16* wbuf, const float* bias, float* outf, u16* outb,
                  int Cout, int h, int wd)
{
  int cocols = (Cout + 63) / 64, Coutpad = cocols * 64;
  dim3 grid((h / 16) * (wd / 16), cocols, 2);
  switch (variant) {
    case 0: k_conv<1,1,1,1><<<grid, TPB, 0, st>>>(in1, c1, in2, c2, wbuf, bias, outf, outb, Cout, Coutpad, h, wd); break;
    case 1: k_conv<1,1,0,1><<<grid, TPB, 0, st>>>(in1, c1, in2, c2, wbuf, bias, outf, outb, Cout, Coutpad, h, wd); break;
    case 2: k_conv<1,1,1,0><<<grid, TPB, 0, st>>>(in1, c1, in2, c2, wbuf, bias, outf, outb, Cout, Coutpad, h, wd); break;
    case 3: k_conv<0,1,1,0><<<grid, TPB, 0, st>>>(in1, c1, in2, c2, wbuf, bias, outf, outb, Cout, Coutpad, h, wd); break;
    case 4: k_conv<2,1,1,0><<<grid, TPB, 0, st>>>(in1, c1, in2, c2, wbuf, bias, outf, outb, Cout, Coutpad, h, wd); break;
    case 5: k_conv<1,0,1,1><<<grid, TPB, 0, st>>>(in1, c1, in2, c2, wbuf, bias, outf, outb, Cout, Coutpad, h, wd); break;
    case 6: k_conv<0,0,0,0><<<grid, TPB, 0, st>>>(in1, c1, in2, c2, wbuf, bias, outf, outb, Cout, Coutpad, h, wd); break;
    default: k_conv<1,0,0,0><<<grid, TPB, 0, st>>>(in1, c1, in2, c2, wbuf, bias, outf, outb, Cout, Coutpad, h, wd); break;
  }
}

static void dconv(hipStream_t st, const float* x, const float* om, const float* mask,
                  int maskC, int maskBase, const float* w, const float* b, float* out,
                  int h, int wd, int sigm, int act)
{
  dim3 grid((h / 8) * (wd / 16), 2, 2);
  if (sigm) {
    if (act) k_dconv5<1,1><<<grid, TPB, 0, st>>>(x, om, mask, maskC, maskBase, w, b, out, h, wd);
    else     k_dconv5<1,0><<<grid, TPB, 0, st>>>(x, om, mask, maskC, maskBase, w, b, out, h, wd);
  } else     k_dconv5<0,0><<<grid, TPB, 0, st>>>(x, om, mask, maskC, maskBase, w, b, out, h, wd);
}

static void up2f(hipStream_t st, const float* in, float* out, int h, int w)
{
  int total = 128 * 4 * h * w;
  k_up2<<<(total + TPB - 1) / TPB, TPB, 0, st>>>(in, out, h, w);
}

extern "C" void kernel_launch(void* const* d_in, const int* in_sizes, int n_in,
                              void* d_out, int out_size, void* d_ws, size_t ws_size,
                              hipStream_t stream)
{
  const float* const* in = (const float* const*)d_in;

  const int HW0 = 192 * 192, HW1 = 96 * 96, HW2 = 48 * 48;
  const size_t N0 = (size_t)2 * HW0 * 64, N1 = (size_t)2 * HW1 * 64, N2 = (size_t)2 * HW2 * 64;

  // ---- workspace layout (with liveness aliases, ~160 MB) ----
  u16* p = (u16*)d_ws;
  u16* nrf0b = p; p += N0;
  u16* rf0b  = p; p += N0;
  u16* swf0b = p; p += N0;
  u16* nrf1b = p; p += N1;
  u16* rf1b  = p; p += N1;
  u16* swf1b = p; p += N1;
  u16* nrf2b = p; p += N2;
  u16* rf2b  = p; p += N2;
  u16* swf2b = p; p += N2;
  u16* Abf   = p; p += N0;
  p = (u16*)(((uintptr_t)p + 15) & ~(uintptr_t)15);
  float* OM   = (float*)p;                                   // 2*216*HW0
  float* EM   = OM + (size_t)2 * 216 * HW0;                  // 2*72*HW0
  float* OF0  = EM + (size_t)2 * 72 * HW0;                   // of0f; later xd0f/xd1f
  float* DN1  = OF0 + (size_t)2 * 64 * HW0;                  // 2*64*HW1
  u16* wp = (u16*)(DN1 + (size_t)2 * 64 * HW1);
  // aliases
  float* UF   = OM + (size_t)2 * 216 * HW0 - (size_t)2 * 64 * HW0;  // OM tail
  float* xdf  = OF0;                                         // xd0f / xd1f (after sh of level)
  float* dn0f = EM;                                          // after sh0

  float* dout = (float*)d_out;
  const size_t L0 = (size_t)2 * 64 * HW0;
  float* out0 = dout;
  float* sh0  = dout + L0;
  float* sh1  = sh0  + L0;
  float* sh2  = sh1  + L0 / 4;
  // scratch aliases inside d_out (dead-before-write regions):
  u16*   Bbf  = (u16*)out0;                                  // overwritten by final dconv
  float* OF1  = sh0;                                         // dead before sh0-dconv writes
  float* OF2  = sh0 + (size_t)2 * 64 * HW1;
  float* DN2  = OF2 + (size_t)2 * 64 * HW2;

  // ---- input conversion (9 tensors) ----
  {
    ToBfArgs ta;
    const float* srcs[9] = {in[0], in[1], in[2], in[3], in[4], in[5], in[6], in[7], in[8]};
    u16* dsts[9] = {nrf0b, rf0b, swf0b, nrf1b, rf1b, swf1b, nrf2b, rf2b, swf2b};
    const int hws[9] = {HW0, HW0, HW0, HW1, HW1, HW1, HW2, HW2, HW2};
    for (int i = 0; i < 9; ++i) { ta.src[i] = srcs[i]; ta.dst[i] = dsts[i]; ta.hw[i] = hws[i]; }
    int maxtot = 2 * HW0 * 8;
    k_tobf_all<<<dim3((maxtot + TPB - 1) / TPB, 9), TPB, 0, stream>>>(ta);
  }

  // ---- weight prep ----
  struct { int arg, cin, cout; } plist[22] = {
    {9,128,64},{11,64,64},{13,64,216},{15,128,64},{17,64,72},
    {21,128,64},{23,64,64},{25,64,216},{27,128,64},{29,64,72},
    {33,128,64},{35,64,64},{37,64,216},{39,128,64},{41,64,72},
    {45,128,64},{47,128,64},{49,128,64},{51,128,64},
    {53,128,64},{55,64,64},{57,64,216}};
  WPrepArgs wa;
  u16* wptr[22];
  int maxtot = 0;
  for (int i = 0; i < 22; ++i) {
    int cin = plist[i].cin, cout = plist[i].cout;
    int cpad = ((cout + 63) / 64) * 64;
    int tot = (cin / 32) * 9 * cpad * 40;
    wa.src[i] = in[plist[i].arg]; wa.dst[i] = wp;
    wa.cin[i] = cin; wa.cout[i] = cout; wa.coutpad[i] = cpad; wa.total[i] = tot;
    wptr[i] = wp; wp += tot;
    if (tot > maxtot) maxtot = tot;
  }
  k_wprep_all<<<dim3((maxtot + TPB - 1) / TPB, 22), TPB, 0, stream>>>(wa);

  u16* w_ocf0 = wptr[0];  u16* w_ocl0 = wptr[1];  u16* w_com0 = wptr[2];
  u16* w_em10 = wptr[3];  u16* w_em20 = wptr[4];
  u16* w_ocf1 = wptr[5];  u16* w_ocl1 = wptr[6];  u16* w_com1 = wptr[7];
  u16* w_em11 = wptr[8];  u16* w_em21 = wptr[9];
  u16* w_ocf2 = wptr[10]; u16* w_ocl2 = wptr[11]; u16* w_com2 = wptr[12];
  u16* w_em12 = wptr[13]; u16* w_em22 = wptr[14];
  u16* w_occ0 = wptr[15]; u16* w_fcc0 = wptr[16];
  u16* w_occ1 = wptr[17]; u16* w_fcc1 = wptr[18];
  u16* w_cas1 = wptr[19]; u16* w_cas2 = wptr[20]; u16* w_casc = wptr[21];

  // ----- level 2 (48x48) -----
  const int h2 = 48, h1 = 96, h0 = 192;
  conv3(stream, 0, nrf2b, 64, rf2b, 64,  w_ocf2, in[34], nullptr, Abf, 64, h2, h2);   // ocf2 -> Abf
  conv3(stream, 2, Abf,   64, nullptr,0, w_ocl2, in[36], OF2, nullptr, 64, h2, h2);   // ocl2 -> of2f
  conv3(stream, 3, swf2b, 64, nullptr,0, w_com2, in[38], OM, nullptr, 216, h2, h2);   // com2 -> OM
  conv3(stream, 5, OF2,   64, swf2b,64,  w_em12, in[40], nullptr, Bbf, 64, h2, h2);   // em12 -> Bbf
  conv3(stream, 4, Bbf,   64, nullptr,0, w_em22, in[42], EM, nullptr, 72, h2, h2);    // em22 -> EM
  dconv(stream, OF2,   OM, EM,  72, 0,   in[43], in[44], sh2, h2, h2, 0, 0);
  dconv(stream, in[6], OM, OM, 216, 144, in[43], in[44], DN2, h2, h2, 1, 1);          // xd2+lrelu = dn2 (x = nrf2)

  // ----- level 1 (96x96) -----
  up2f(stream, OF2, UF, h2, h2);                                                      // up2(of2)
  conv3(stream, 0, nrf1b, 64, rf1b, 64,  w_ocf1, in[22], nullptr, Abf, 64, h1, h1);   // ocf1 -> Abf
  conv3(stream, 1, Abf,   64, UF,   64,  w_occ1, in[50], nullptr, Bbf, 64, h1, h1);   // occ1 -> Bbf
  conv3(stream, 2, Bbf,   64, nullptr,0, w_ocl1, in[24], OF1, nullptr, 64, h1, h1);   // ocl1 -> of1f
  conv3(stream, 3, swf1b, 64, nullptr,0, w_com1, in[26], OM, nullptr, 216, h1, h1);   // com1 -> OM
  conv3(stream, 5, OF1,   64, swf1b,64,  w_em11, in[28], nullptr, Abf, 64, h1, h1);   // em11 -> Abf
  conv3(stream, 4, Abf,   64, nullptr,0, w_em21, in[30], EM, nullptr, 72, h1, h1);    // em21 -> EM
  dconv(stream, OF1,   OM, EM,  72, 0,   in[31], in[32], sh1, h1, h1, 0, 0);
  dconv(stream, in[3], OM, OM, 216, 144, in[31], in[32], xdf, h1, h1, 1, 0);          // xd1 -> OF0 region (x = nrf1)
  up2f(stream, DN2, UF, h2, h2);                                                      // up2(dn2)
  conv3(stream, 7, xdf,  64, UF,    64,  w_fcc1, in[52], DN1, nullptr, 64, h1, h1);   // fcc1 -> dn1

  // ----- level 0 (192x192) -----
  up2f(stream, OF1, UF, h1, h1);                                                      // up2(of1)
  conv3(stream, 0, nrf0b, 64, rf0b, 64,  w_ocf0, in[10], nullptr, Abf, 64, h0, h0);   // ocf0 -> Abf
  conv3(stream, 1, Abf,   64, UF,   64,  w_occ0, in[46], nullptr, Bbf, 64, h0, h0);   // occ0 -> Bbf
  conv3(stream, 2, Bbf,   64, nullptr,0, w_ocl0, in[12], OF0, nullptr, 64, h0, h0);   // ocl0 -> of0f
  conv3(stream, 3, swf0b, 64, nullptr,0, w_com0, in[14], OM, nullptr, 216, h0, h0);   // com0 -> OM
  conv3(stream, 5, OF0,   64, swf0b,64,  w_em10, in[16], nullptr, Abf, 64, h0, h0);   // em10 -> Abf
  conv3(stream, 4, Abf,   64, nullptr,0, w_em20, in[18], EM, nullptr, 72, h0, h0);    // em20 -> EM
  dconv(stream, OF0,   OM, EM,  72, 0,   in[19], in[20], sh0, h0, h0, 0, 0);
  dconv(stream, in[0], OM, OM, 216, 144, in[19], in[20], xdf, h0, h0, 1, 0);          // xd0 -> OF0 region (x = nrf0)
  up2f(stream, DN1, UF, h1, h1);                                                      // up2(dn1)
  conv3(stream, 6, xdf,  64, UF,    64,  w_fcc0, in[48], dn0f, nullptr, 64, h0, h0);  // fcc0 -> dn0 (EM)
  conv3(stream, 5, dn0f, 64, rf0b,  64,  w_cas1, in[54], nullptr, Abf, 64, h0, h0);   // cas1 -> Abf
  conv3(stream, 0, Abf,  64, nullptr,0,  w_cas2, in[56], nullptr, Bbf, 64, h0, h0);   // cas2 -> Bbf
  conv3(stream, 3, Bbf,  64, nullptr,0,  w_casc, in[58], OM, nullptr, 216, h0, h0);   // cas_com -> OM
  dconv(stream, dn0f, OM, OM, 216, 144, in[59], in[60], out0, h0, h0, 1, 1);          // final
}